// Round 16
// baseline (32.017 us; speedup 1.0000x reference)
//
#include <hip/hip_runtime.h>

#define NB 2
#define NH 4
#define NS 512
#define ND 16
#define NF 32

typedef float v4f __attribute__((ext_vector_type(4)));
typedef float v2f __attribute__((ext_vector_type(2)));

// workspace layouts:
//   hq_rm : [bh][s 0..511][f 0..63]  row-major (f<32: @A, f>=32: @B+b1)
//   hkp   : [bh][half(A=0,B=1)][f4 0..7][s 0..511][c 0..3]  paired-x4
//   vpt   : [bh][d 0..15][s 0..511]
//   cq_ws : [bh][half][s]  partial Cq = sum_f n2[f]*hq_half[f]
//   ck_ws : [bh][half][s]  partial Ck = sum_f n2[f]*hk_half[f]

// ---------------- Kernel 1: fused projections (+ n2-dot partials) ----------------
__global__ __launch_bounds__(256) void k_proj(
    const float* __restrict__ q, const float* __restrict__ kin, const float* __restrict__ v,
    const float* __restrict__ Wq, const float* __restrict__ bq,
    const float* __restrict__ Wk, const float* __restrict__ bk,
    const float* __restrict__ Wv, const float* __restrict__ bv,
    const float* __restrict__ N1, const float* __restrict__ b1,
    const float* __restrict__ N2,
    float* __restrict__ hq_rm, float* __restrict__ hkp, float* __restrict__ vpt,
    float* __restrict__ cq_ws, float* __restrict__ ck_ws)
{
    __shared__ float m_s[16 * 32];
    __shared__ float c_s[32];
    __shared__ float trans_s[256 * 33];   // [s_loc][f 0..31]

    const int bid = blockIdx.x;
    const int job = bid % 5;
    const int sc  = (bid / 5) & 1;
    const int bh  = bid / 10;
    const int t   = threadIdx.x;

    const float* W    = (job < 2) ? Wq : (job < 4 ? Wk : Wv);
    const float* bias = (job < 2) ? bq : (job < 4 ? bk : bv);
    const float* x    = (job < 2) ? q  : (job < 4 ? kin : v);

    if (job < 4) {
        const int noff = (job & 1) * 16;
        for (int i = t; i < 512; i += 256) {
            int e = i >> 5, f = i & 31;
            float m = 0.f;
#pragma unroll
            for (int d = 0; d < 16; ++d)
                m = fmaf(W[e * 16 + d], N1[(noff + d) * 32 + f], m);
            m_s[i] = m;
        }
        if (t < 32) {
            float c = (job & 1) ? b1[t] : 0.f;
#pragma unroll
            for (int d = 0; d < 16; ++d)
                c = fmaf(bias[d], N1[(noff + d) * 32 + t], c);
            c_s[t] = c;
        }
    } else {
        int e = t >> 4, d = t & 15;
        m_s[e * 32 + d] = W[e * 16 + d];
        if (t < 16) c_s[t] = bias[t];
    }
    __syncthreads();

    const int s = sc * 256 + t;
    const int r = bh * NS + s;

    float xv[16];
    const float4* x4 = (const float4*)(x + (size_t)r * 16);
#pragma unroll
    for (int j = 0; j < 4; ++j) {
        float4 a = x4[j];
        xv[4*j] = a.x; xv[4*j+1] = a.y; xv[4*j+2] = a.z; xv[4*j+3] = a.w;
    }

    if (job < 4) {
        float h[32];
#pragma unroll
        for (int f = 0; f < 32; ++f) h[f] = c_s[f];
#pragma unroll
        for (int e = 0; e < 16; ++e)
#pragma unroll
            for (int f = 0; f < 32; ++f)
                h[f] = fmaf(xv[e], m_s[e * 32 + f], h[f]);
#pragma unroll
        for (int f = 0; f < 32; ++f) trans_s[t * 33 + f] = h[f];

        // n2-dot partial for this row/half (uniform N2 -> scalar loads)
        float cpart = 0.f;
#pragma unroll
        for (int f = 0; f < 32; ++f) cpart = fmaf(N2[f], h[f], cpart);
        if (job < 2) cq_ws[bh * 1024 + (job & 1) * 512 + s] = cpart;
        else         ck_ws[bh * 1024 + (job & 1) * 512 + s] = cpart;

        __syncthreads();

        if (job < 2) {
            float* outb = hq_rm + (((size_t)(bh * NS + sc * 256)) << 6) + (job & 1) * 32;
#pragma unroll
            for (int it = 0; it < 32; ++it) {
                int j = it * 256 + t;            // 0..8191 = 256 s x 32 f
                int sl = j >> 5, f = j & 31;
                outb[((size_t)sl << 6) + f] = trans_s[sl * 33 + f];
            }
        } else {
            float* outb = hkp + (size_t)bh * 32768 + (size_t)(job & 1) * 16384 + sc * 1024;
#pragma unroll
            for (int it = 0; it < 32; ++it) {
                int i = it * 256 + t;            // 0..8191 = 8 f4 x 256 s x 4 c
                int f4 = i >> 10, rem = i & 1023;
                int sl = rem >> 2, c = rem & 3;
                outb[(size_t)f4 * 2048 + rem] = trans_s[sl * 33 + f4 * 4 + c];
            }
        }
    } else {
        float* outb = vpt + (size_t)bh * 8192;
        float h[16];
#pragma unroll
        for (int d = 0; d < 16; ++d) h[d] = c_s[d];
#pragma unroll
        for (int e = 0; e < 16; ++e)
#pragma unroll
            for (int d = 0; d < 16; ++d)
                h[d] = fmaf(xv[e], m_s[e * 32 + d], h[d]);
#pragma unroll
        for (int d = 0; d < 16; ++d)
            outb[(size_t)d * NS + s] = h[d];
    }
}

// ---------------- Kernel 2: fused scores + softmax + PV + Wo ----------------
// grid 512 = 8 bh x 64 q-tiles (8 qi); 512 threads (8 waves); thread owns one k.
// Score via relu(x) = (x+|x|)/2:  s = 0.5*(Cq + Ck + sum n2*(|t1|+|t2|)) + 2*b2.
// Phase 1 packed: v_pk_add + v_pk_max(t,-t) + v_pk_fma = 3 instr / 2 floats.
__global__ __launch_bounds__(512) void k_fused(
    const float* __restrict__ hq_rm, const float* __restrict__ hkp,
    const float* __restrict__ vpt,
    const float* __restrict__ cq_ws, const float* __restrict__ ck_ws,
    const float* __restrict__ N2, const float* __restrict__ b2,
    const float* __restrict__ mask,
    const float* __restrict__ Wo, const float* __restrict__ bo,
    float* __restrict__ attn, float* __restrict__ out)
{
    __shared__ __align__(16) float attn_s[8 * 516];  // [qi][k]
    __shared__ float wo_s[256];
    __shared__ float bo_s[16];
    __shared__ float ov_s[128];                      // [qi][d]
    __shared__ float part_s[128 * 17];               // [qi*16+d][koct]
    __shared__ float redm[64];                       // [qi][wave] max
    __shared__ float reds[64];                       // [qi][wave] sum(exp(s-m_w))

    const int bh  = blockIdx.x >> 6;
    const int q0  = (blockIdx.x & 63) << 3;
    const int tid = threadIdx.x;
    const int wave = tid >> 6, lane = tid & 63;
    const int k = tid;
    const size_t base = (size_t)bh * 32768;

    const v4f* hkb = (const v4f*)(hkp + base + (size_t)k * 4);   // f4 stride = 512 v4f
    v2f n2v[16];
#pragma unroll
    for (int j = 0; j < 16; ++j) n2v[j] = (v2f){ N2[2*j], N2[2*j+1] };
    const float b2v = 2.0f * b2[0];

    // per-thread Ck (coalesced), per-qi Cq (uniform)
    const float ckv = ck_ws[bh * 1024 + k] + ck_ws[bh * 1024 + 512 + k];

    if (tid < 256) wo_s[tid] = Wo[tid];
    if (tid < 16)  bo_s[tid] = bo[tid];
    __syncthreads();

    // ---- pass 1: hk = B' half; abs-partial sum n2*|hqA + hkB'| (packed) ----
    v4f hk4[8];
#pragma unroll
    for (int f4 = 0; f4 < 8; ++f4) hk4[f4] = hkb[4096 + f4 * 512];   // B half
    const v2f* hk2 = (const v2f*)hk4;                                 // 16 pairs

    float sreg[8];
#pragma unroll
    for (int qi = 0; qi < 8; ++qi) {
        const v2f* hq2 = (const v2f*)(hq_rm + (((size_t)(bh * NS + q0 + qi)) << 6)); // pairs 0..15 = A
        v2f acc0 = (v2f)0.f, acc1 = (v2f)0.f;
#pragma unroll
        for (int f2 = 0; f2 < 16; f2 += 2) {
            v2f ta = hq2[f2]     + hk2[f2];
            v2f tb = hq2[f2 + 1] + hk2[f2 + 1];
            v2f aa = __builtin_elementwise_max(ta, -ta);   // v_pk_max_f32(t, -t) = |t|
            v2f ab = __builtin_elementwise_max(tb, -tb);
            acc0 = __builtin_elementwise_fma(n2v[f2],     aa, acc0);
            acc1 = __builtin_elementwise_fma(n2v[f2 + 1], ab, acc1);
        }
        v2f accs = acc0 + acc1;
        sreg[qi] = accs.x + accs.y;
    }

    // ---- pass 2: hk = A half; finish scores, wave max + exp-sum reduce ----
#pragma unroll
    for (int f4 = 0; f4 < 8; ++f4) hk4[f4] = hkb[f4 * 512];          // A half

    const float* mbase = mask + (size_t)(bh >> 2) * NS * NS;   // H=4
    float mreg[8];
#pragma unroll
    for (int qi = 0; qi < 8; ++qi) mreg[qi] = mbase[(size_t)(q0 + qi) * NS + k];

#pragma unroll
    for (int qi = 0; qi < 8; ++qi) {
        const v2f* hq2 = (const v2f*)(hq_rm + (((size_t)(bh * NS + q0 + qi)) << 6)) + 16; // B half
        v2f acc0 = (v2f)0.f, acc1 = (v2f)0.f;
#pragma unroll
        for (int f2 = 0; f2 < 16; f2 += 2) {
            v2f ta = hq2[f2]     + hk2[f2];
            v2f tb = hq2[f2 + 1] + hk2[f2 + 1];
            v2f aa = __builtin_elementwise_max(ta, -ta);
            v2f ab = __builtin_elementwise_max(tb, -tb);
            acc0 = __builtin_elementwise_fma(n2v[f2],     aa, acc0);
            acc1 = __builtin_elementwise_fma(n2v[f2 + 1], ab, acc1);
        }
        v2f accs = acc0 + acc1;
        const float cqv = cq_ws[bh * 1024 + q0 + qi] + cq_ws[bh * 1024 + 512 + q0 + qi];
        float absum = sreg[qi] + accs.x + accs.y;
        float s = fmaf(0.5f, cqv + ckv + absum, b2v);
        s = fmaf(mreg[qi], -1e9f, s);

        float m = s;
#pragma unroll
        for (int off = 32; off > 0; off >>= 1) m = fmaxf(m, __shfl_xor(m, off));
        float e = __expf(s - m);
        sreg[qi] = s - m;
        float ss = e;
#pragma unroll
        for (int off = 32; off > 0; off >>= 1) ss += __shfl_xor(ss, off);
        if (lane == 0) { redm[qi * 8 + wave] = m; reds[qi * 8 + wave] = ss; }
    }
    __syncthreads();

    // ---- block combine, normalize, write attn ----
#pragma unroll
    for (int qi = 0; qi < 8; ++qi) {
        float M = redm[qi * 8];
#pragma unroll
        for (int w = 1; w < 8; ++w) M = fmaxf(M, redm[qi * 8 + w]);
        float tot = 0.f;
#pragma unroll
        for (int w = 0; w < 8; ++w)
            tot = fmaf(reds[qi * 8 + w], __expf(redm[qi * 8 + w] - M), tot);
        float mw = redm[qi * 8 + wave];
        float p = __expf(sreg[qi] + (mw - M)) * __builtin_amdgcn_rcpf(tot);
        attn[(size_t)(bh * NS + q0 + qi) * NS + k] = p;
        attn_s[qi * 516 + k] = p;
    }
    __syncthreads();

    // ---- PV: thread = (qi_p = tid&7, dgrp = (tid>>3)&3, koct = tid>>5) ----
    {
        const int qi_p = tid & 7;
        const int dgrp = (tid >> 3) & 3;
        const int koct = tid >> 5;                          // 0..15, 8 float4 each
        const float4* a4 = (const float4*)attn_s;           // row stride 129
        const float4* v4 = (const float4*)(vpt + (size_t)bh * 8192); // [d][128]
        float acc0 = 0.f, acc1 = 0.f, acc2 = 0.f, acc3 = 0.f;
#pragma unroll
        for (int kq = 0; kq < 8; ++kq) {
            const int k4 = koct * 8 + kq;
            float4 av = a4[qi_p * 129 + k4];
            float4 w0 = v4[(dgrp * 4 + 0) * 128 + k4];
            float4 w1 = v4[(dgrp * 4 + 1) * 128 + k4];
            float4 w2 = v4[(dgrp * 4 + 2) * 128 + k4];
            float4 w3 = v4[(dgrp * 4 + 3) * 128 + k4];
            acc0 = fmaf(av.x, w0.x, fmaf(av.y, w0.y, fmaf(av.z, w0.z, fmaf(av.w, w0.w, acc0))));
            acc1 = fmaf(av.x, w1.x, fmaf(av.y, w1.y, fmaf(av.z, w1.z, fmaf(av.w, w1.w, acc1))));
            acc2 = fmaf(av.x, w2.x, fmaf(av.y, w2.y, fmaf(av.z, w2.z, fmaf(av.w, w2.w, acc2))));
            acc3 = fmaf(av.x, w3.x, fmaf(av.y, w3.y, fmaf(av.z, w3.z, fmaf(av.w, w3.w, acc3))));
        }
        part_s[(qi_p * 16 + dgrp * 4 + 0) * 17 + koct] = acc0;
        part_s[(qi_p * 16 + dgrp * 4 + 1) * 17 + koct] = acc1;
        part_s[(qi_p * 16 + dgrp * 4 + 2) * 17 + koct] = acc2;
        part_s[(qi_p * 16 + dgrp * 4 + 3) * 17 + koct] = acc3;
    }
    __syncthreads();

    // ---- combine k-partials ----
    if (tid < 128) {
        float ov = 0.f;
#pragma unroll
        for (int kh = 0; kh < 16; ++kh) ov += part_s[tid * 17 + kh];
        ov_s[tid] = ov;
    }
    __syncthreads();

    // ---- out = ov @ Wo + bo ----
    if (tid < 128) {
        const int qi2 = tid >> 4, d = tid & 15;
        float res = bo_s[d];
#pragma unroll
        for (int e = 0; e < 16; ++e)
            res = fmaf(ov_s[qi2 * 16 + e], wo_s[e * 16 + d], res);
        out[(size_t)(bh * NS + q0 + qi2) * 16 + d] = res;
    }
}

extern "C" void kernel_launch(void* const* d_in, const int* in_sizes, int n_in,
                              void* d_out, int out_size, void* d_ws, size_t ws_size,
                              hipStream_t stream)
{
    const float* v    = (const float*)d_in[0];
    const float* k    = (const float*)d_in[1];
    const float* q    = (const float*)d_in[2];
    const float* mask = (const float*)d_in[3];
    const float* Wq   = (const float*)d_in[4];
    const float* bq   = (const float*)d_in[5];
    const float* Wk   = (const float*)d_in[6];
    const float* bk   = (const float*)d_in[7];
    const float* Wv   = (const float*)d_in[8];
    const float* bv   = (const float*)d_in[9];
    const float* Wo   = (const float*)d_in[10];
    const float* bo   = (const float*)d_in[11];
    const float* N1   = (const float*)d_in[12];
    const float* b1   = (const float*)d_in[13];
    const float* N2   = (const float*)d_in[14];
    const float* b2   = (const float*)d_in[15];

    float* out  = (float*)d_out;                   // 65536 floats
    float* attn = out + (size_t)NB*NH*NS*ND;       // 2097152 floats

    float* hq_rm = (float*)d_ws;                   // 262144 floats
    float* hkp   = hq_rm + (size_t)8 * 32768;      // 262144 floats
    float* vpt   = hkp + (size_t)8 * 32768;        // 65536 floats
    float* cq_ws = vpt + (size_t)8 * 8192;         // 8192 floats
    float* ck_ws = cq_ws + 8192;                   // 8192 floats

    k_proj <<<80, 256, 0, stream>>>(q, k, v, Wq, bq, Wk, bk, Wv, bv, N1, b1, N2,
                                    hq_rm, hkp, vpt, cq_ws, ck_ws);
    k_fused<<<512, 512, 0, stream>>>(hq_rm, hkp, vpt, cq_ws, ck_ws,
                                     N2, b2, mask, Wo, bo, attn, out);
}

// Round 17
// 31.195 us; speedup vs baseline: 1.0264x; 1.0264x over previous
//
#include <hip/hip_runtime.h>

#define NB 2
#define NH 4
#define NS 512
#define ND 16
#define NF 32

typedef float v4f __attribute__((ext_vector_type(4)));

// workspace layouts:
//   hq_rm : [bh][s 0..511][f 0..63]  row-major (f<32: @A, f>=32: @B+b1)
//   hkp   : [bh][half(A=0,B=1)][f4 0..7][s 0..511][c 0..3]  paired-x4
//   vpt   : [bh][d 0..15][s 0..511]
//   cq_ws : [bh][half][s]  partial Cq = sum_f n2[f]*hq_half[f]
//   ck_ws : [bh][half][s]  partial Ck = sum_f n2[f]*hk_half[f]

// ---------------- Kernel 1: fused projections (+ n2-dot partials) ----------------
__global__ __launch_bounds__(256) void k_proj(
    const float* __restrict__ q, const float* __restrict__ kin, const float* __restrict__ v,
    const float* __restrict__ Wq, const float* __restrict__ bq,
    const float* __restrict__ Wk, const float* __restrict__ bk,
    const float* __restrict__ Wv, const float* __restrict__ bv,
    const float* __restrict__ N1, const float* __restrict__ b1,
    const float* __restrict__ N2,
    float* __restrict__ hq_rm, float* __restrict__ hkp, float* __restrict__ vpt,
    float* __restrict__ cq_ws, float* __restrict__ ck_ws)
{
    __shared__ float m_s[16 * 32];
    __shared__ float c_s[32];
    __shared__ float trans_s[256 * 33];   // [s_loc][f 0..31]

    const int bid = blockIdx.x;
    const int job = bid % 5;
    const int sc  = (bid / 5) & 1;
    const int bh  = bid / 10;
    const int t   = threadIdx.x;

    const float* W    = (job < 2) ? Wq : (job < 4 ? Wk : Wv);
    const float* bias = (job < 2) ? bq : (job < 4 ? bk : bv);
    const float* x    = (job < 2) ? q  : (job < 4 ? kin : v);

    if (job < 4) {
        const int noff = (job & 1) * 16;
        for (int i = t; i < 512; i += 256) {
            int e = i >> 5, f = i & 31;
            float m = 0.f;
#pragma unroll
            for (int d = 0; d < 16; ++d)
                m = fmaf(W[e * 16 + d], N1[(noff + d) * 32 + f], m);
            m_s[i] = m;
        }
        if (t < 32) {
            float c = (job & 1) ? b1[t] : 0.f;
#pragma unroll
            for (int d = 0; d < 16; ++d)
                c = fmaf(bias[d], N1[(noff + d) * 32 + t], c);
            c_s[t] = c;
        }
    } else {
        int e = t >> 4, d = t & 15;
        m_s[e * 32 + d] = W[e * 16 + d];
        if (t < 16) c_s[t] = bias[t];
    }
    __syncthreads();

    const int s = sc * 256 + t;
    const int r = bh * NS + s;

    float xv[16];
    const float4* x4 = (const float4*)(x + (size_t)r * 16);
#pragma unroll
    for (int j = 0; j < 4; ++j) {
        float4 a = x4[j];
        xv[4*j] = a.x; xv[4*j+1] = a.y; xv[4*j+2] = a.z; xv[4*j+3] = a.w;
    }

    if (job < 4) {
        float h[32];
#pragma unroll
        for (int f = 0; f < 32; ++f) h[f] = c_s[f];
#pragma unroll
        for (int e = 0; e < 16; ++e)
#pragma unroll
            for (int f = 0; f < 32; ++f)
                h[f] = fmaf(xv[e], m_s[e * 32 + f], h[f]);
#pragma unroll
        for (int f = 0; f < 32; ++f) trans_s[t * 33 + f] = h[f];

        // n2-dot partial for this row/half (uniform N2 -> scalar loads)
        float cpart = 0.f;
#pragma unroll
        for (int f = 0; f < 32; ++f) cpart = fmaf(N2[f], h[f], cpart);
        if (job < 2) cq_ws[bh * 1024 + (job & 1) * 512 + s] = cpart;
        else         ck_ws[bh * 1024 + (job & 1) * 512 + s] = cpart;

        __syncthreads();

        if (job < 2) {
            float* outb = hq_rm + (((size_t)(bh * NS + sc * 256)) << 6) + (job & 1) * 32;
#pragma unroll
            for (int it = 0; it < 32; ++it) {
                int j = it * 256 + t;            // 0..8191 = 256 s x 32 f
                int sl = j >> 5, f = j & 31;
                outb[((size_t)sl << 6) + f] = trans_s[sl * 33 + f];
            }
        } else {
            float* outb = hkp + (size_t)bh * 32768 + (size_t)(job & 1) * 16384 + sc * 1024;
#pragma unroll
            for (int it = 0; it < 32; ++it) {
                int i = it * 256 + t;            // 0..8191 = 8 f4 x 256 s x 4 c
                int f4 = i >> 10, rem = i & 1023;
                int sl = rem >> 2, c = rem & 3;
                outb[(size_t)f4 * 2048 + rem] = trans_s[sl * 33 + f4 * 4 + c];
            }
        }
    } else {
        float* outb = vpt + (size_t)bh * 8192;
        float h[16];
#pragma unroll
        for (int d = 0; d < 16; ++d) h[d] = c_s[d];
#pragma unroll
        for (int e = 0; e < 16; ++e)
#pragma unroll
            for (int d = 0; d < 16; ++d)
                h[d] = fmaf(xv[e], m_s[e * 32 + d], h[d]);
#pragma unroll
        for (int d = 0; d < 16; ++d)
            outb[(size_t)d * NS + s] = h[d];
    }
}

// ---------------- Kernel 2: fused scores + softmax + PV + Wo ----------------
// grid 512 = 8 bh x 64 q-tiles (8 qi); 512 threads (8 waves); thread owns one k.
// Score via relu(x) = (x+|x|)/2:  s = 0.5*(Cq + Ck + sum n2*(|t1|+|t2|)) + 2*b2.
// Inner loop = add + fma(|x| modifier): best verified form (R15, 31.4 us).
__global__ __launch_bounds__(512) void k_fused(
    const float* __restrict__ hq_rm, const float* __restrict__ hkp,
    const float* __restrict__ vpt,
    const float* __restrict__ cq_ws, const float* __restrict__ ck_ws,
    const float* __restrict__ N2, const float* __restrict__ b2,
    const float* __restrict__ mask,
    const float* __restrict__ Wo, const float* __restrict__ bo,
    float* __restrict__ attn, float* __restrict__ out)
{
    __shared__ __align__(16) float attn_s[8 * 516];  // [qi][k]
    __shared__ float wo_s[256];
    __shared__ float bo_s[16];
    __shared__ float ov_s[128];                      // [qi][d]
    __shared__ float part_s[128 * 17];               // [qi*16+d][koct]
    __shared__ float redm[64];                       // [qi][wave] max
    __shared__ float reds[64];                       // [qi][wave] sum(exp(s-m_w))

    const int bh  = blockIdx.x >> 6;
    const int q0  = (blockIdx.x & 63) << 3;
    const int tid = threadIdx.x;
    const int wave = tid >> 6, lane = tid & 63;
    const int k = tid;
    const size_t base = (size_t)bh * 32768;

    const v4f* hkb = (const v4f*)(hkp + base + (size_t)k * 4);   // f4 stride = 512 v4f
    float n2s[32];
#pragma unroll
    for (int f = 0; f < 32; ++f) n2s[f] = N2[f];
    const float b2v = 2.0f * b2[0];

    // per-thread Ck (coalesced), per-qi Cq (uniform)
    const float ckv = ck_ws[bh * 1024 + k] + ck_ws[bh * 1024 + 512 + k];

    if (tid < 256) wo_s[tid] = Wo[tid];
    if (tid < 16)  bo_s[tid] = bo[tid];
    __syncthreads();

    // ---- pass 1: hk = B' half; abs-partial sum n2*|hqA + hkB'| ----
    v4f hk4[8];
#pragma unroll
    for (int f4 = 0; f4 < 8; ++f4) hk4[f4] = hkb[4096 + f4 * 512];   // B half

    float sreg[8];
#pragma unroll
    for (int qi = 0; qi < 8; ++qi) {
        const v4f* hq4 = (const v4f*)(hq_rm + (((size_t)(bh * NS + q0 + qi)) << 6));
        float a0 = 0.f, a1 = 0.f, a2 = 0.f, a3 = 0.f;
#pragma unroll
        for (int f4 = 0; f4 < 8; ++f4) {
            v4f t1 = hq4[f4] + hk4[f4];                 // hqA + hkB'
            a0 = fmaf(n2s[4*f4    ], __builtin_fabsf(t1.x), a0);
            a1 = fmaf(n2s[4*f4 + 1], __builtin_fabsf(t1.y), a1);
            a2 = fmaf(n2s[4*f4 + 2], __builtin_fabsf(t1.z), a2);
            a3 = fmaf(n2s[4*f4 + 3], __builtin_fabsf(t1.w), a3);
        }
        sreg[qi] = (a0 + a1) + (a2 + a3);
    }

    // ---- pass 2: hk = A half; finish scores, wave max + exp-sum reduce ----
#pragma unroll
    for (int f4 = 0; f4 < 8; ++f4) hk4[f4] = hkb[f4 * 512];          // A half

    const float* mbase = mask + (size_t)(bh >> 2) * NS * NS;   // H=4
    float mreg[8];
#pragma unroll
    for (int qi = 0; qi < 8; ++qi) mreg[qi] = mbase[(size_t)(q0 + qi) * NS + k];

#pragma unroll
    for (int qi = 0; qi < 8; ++qi) {
        const v4f* hq4 = (const v4f*)(hq_rm + (((size_t)(bh * NS + q0 + qi)) << 6));
        float a0 = 0.f, a1 = 0.f, a2 = 0.f, a3 = 0.f;
#pragma unroll
        for (int f4 = 0; f4 < 8; ++f4) {
            v4f t2 = hq4[8 + f4] + hk4[f4];             // hqB' + hkA
            a0 = fmaf(n2s[4*f4    ], __builtin_fabsf(t2.x), a0);
            a1 = fmaf(n2s[4*f4 + 1], __builtin_fabsf(t2.y), a1);
            a2 = fmaf(n2s[4*f4 + 2], __builtin_fabsf(t2.z), a2);
            a3 = fmaf(n2s[4*f4 + 3], __builtin_fabsf(t2.w), a3);
        }
        const float cqv = cq_ws[bh * 1024 + q0 + qi] + cq_ws[bh * 1024 + 512 + q0 + qi];
        float absum = sreg[qi] + (a0 + a1) + (a2 + a3);
        float s = fmaf(0.5f, cqv + ckv + absum, b2v);
        s = fmaf(mreg[qi], -1e9f, s);

        float m = s;
#pragma unroll
        for (int off = 32; off > 0; off >>= 1) m = fmaxf(m, __shfl_xor(m, off));
        float e = __expf(s - m);
        sreg[qi] = s - m;
        float ss = e;
#pragma unroll
        for (int off = 32; off > 0; off >>= 1) ss += __shfl_xor(ss, off);
        if (lane == 0) { redm[qi * 8 + wave] = m; reds[qi * 8 + wave] = ss; }
    }
    __syncthreads();

    // ---- block combine, normalize, write attn ----
#pragma unroll
    for (int qi = 0; qi < 8; ++qi) {
        float M = redm[qi * 8];
#pragma unroll
        for (int w = 1; w < 8; ++w) M = fmaxf(M, redm[qi * 8 + w]);
        float tot = 0.f;
#pragma unroll
        for (int w = 0; w < 8; ++w)
            tot = fmaf(reds[qi * 8 + w], __expf(redm[qi * 8 + w] - M), tot);
        float mw = redm[qi * 8 + wave];
        float p = __expf(sreg[qi] + (mw - M)) * __builtin_amdgcn_rcpf(tot);
        attn[(size_t)(bh * NS + q0 + qi) * NS + k] = p;
        attn_s[qi * 516 + k] = p;
    }
    __syncthreads();

    // ---- PV: thread = (qi_p = tid&7, dgrp = (tid>>3)&3, koct = tid>>5) ----
    {
        const int qi_p = tid & 7;
        const int dgrp = (tid >> 3) & 3;
        const int koct = tid >> 5;                          // 0..15, 8 float4 each
        const float4* a4 = (const float4*)attn_s;           // row stride 129
        const float4* v4 = (const float4*)(vpt + (size_t)bh * 8192); // [d][128]
        float acc0 = 0.f, acc1 = 0.f, acc2 = 0.f, acc3 = 0.f;
#pragma unroll
        for (int kq = 0; kq < 8; ++kq) {
            const int k4 = koct * 8 + kq;
            float4 av = a4[qi_p * 129 + k4];
            float4 w0 = v4[(dgrp * 4 + 0) * 128 + k4];
            float4 w1 = v4[(dgrp * 4 + 1) * 128 + k4];
            float4 w2 = v4[(dgrp * 4 + 2) * 128 + k4];
            float4 w3 = v4[(dgrp * 4 + 3) * 128 + k4];
            acc0 = fmaf(av.x, w0.x, fmaf(av.y, w0.y, fmaf(av.z, w0.z, fmaf(av.w, w0.w, acc0))));
            acc1 = fmaf(av.x, w1.x, fmaf(av.y, w1.y, fmaf(av.z, w1.z, fmaf(av.w, w1.w, acc1))));
            acc2 = fmaf(av.x, w2.x, fmaf(av.y, w2.y, fmaf(av.z, w2.z, fmaf(av.w, w2.w, acc2))));
            acc3 = fmaf(av.x, w3.x, fmaf(av.y, w3.y, fmaf(av.z, w3.z, fmaf(av.w, w3.w, acc3))));
        }
        part_s[(qi_p * 16 + dgrp * 4 + 0) * 17 + koct] = acc0;
        part_s[(qi_p * 16 + dgrp * 4 + 1) * 17 + koct] = acc1;
        part_s[(qi_p * 16 + dgrp * 4 + 2) * 17 + koct] = acc2;
        part_s[(qi_p * 16 + dgrp * 4 + 3) * 17 + koct] = acc3;
    }
    __syncthreads();

    // ---- combine k-partials ----
    if (tid < 128) {
        float ov = 0.f;
#pragma unroll
        for (int kh = 0; kh < 16; ++kh) ov += part_s[tid * 17 + kh];
        ov_s[tid] = ov;
    }
    __syncthreads();

    // ---- out = ov @ Wo + bo ----
    if (tid < 128) {
        const int qi2 = tid >> 4, d = tid & 15;
        float res = bo_s[d];
#pragma unroll
        for (int e = 0; e < 16; ++e)
            res = fmaf(ov_s[qi2 * 16 + e], wo_s[e * 16 + d], res);
        out[(size_t)(bh * NS + q0 + qi2) * 16 + d] = res;
    }
}

extern "C" void kernel_launch(void* const* d_in, const int* in_sizes, int n_in,
                              void* d_out, int out_size, void* d_ws, size_t ws_size,
                              hipStream_t stream)
{
    const float* v    = (const float*)d_in[0];
    const float* k    = (const float*)d_in[1];
    const float* q    = (const float*)d_in[2];
    const float* mask = (const float*)d_in[3];
    const float* Wq   = (const float*)d_in[4];
    const float* bq   = (const float*)d_in[5];
    const float* Wk   = (const float*)d_in[6];
    const float* bk   = (const float*)d_in[7];
    const float* Wv   = (const float*)d_in[8];
    const float* bv   = (const float*)d_in[9];
    const float* Wo   = (const float*)d_in[10];
    const float* bo   = (const float*)d_in[11];
    const float* N1   = (const float*)d_in[12];
    const float* b1   = (const float*)d_in[13];
    const float* N2   = (const float*)d_in[14];
    const float* b2   = (const float*)d_in[15];

    float* out  = (float*)d_out;                   // 65536 floats
    float* attn = out + (size_t)NB*NH*NS*ND;       // 2097152 floats

    float* hq_rm = (float*)d_ws;                   // 262144 floats
    float* hkp   = hq_rm + (size_t)8 * 32768;      // 262144 floats
    float* vpt   = hkp + (size_t)8 * 32768;        // 65536 floats
    float* cq_ws = vpt + (size_t)8 * 8192;         // 8192 floats
    float* ck_ws = cq_ws + 8192;                   // 8192 floats

    k_proj <<<80, 256, 0, stream>>>(q, k, v, Wq, bq, Wk, bk, Wv, bv, N1, b1, N2,
                                    hq_rm, hkp, vpt, cq_ws, ck_ws);
    k_fused<<<512, 512, 0, stream>>>(hq_rm, hkp, vpt, cq_ws, ck_ws,
                                     N2, b2, mask, Wo, bo, attn, out);
}